// Round 4
// baseline (166.851 us; speedup 1.0000x reference)
//
#include <hip/hip_runtime.h>

#define NS 64     // samples per batch
#define D  256    // hidden dims
#define O  10     // output dim
#define TK 32     // GEMM K-chunk
#define LSTR 36   // LDS row stride (TK + 4 pad, 16B-aligned, conflict-free)

// ============ K1: fused forward (L1+L2+M2 build) + x-dots =================
// Blocks 0..15: 8 samples each. Thread t = output column. A-operands are
// wave-uniform global reads (scalar-cache path), W loads coalesced across t.
// Blocks 16..31: x-dots, 4 n-rows each.
__global__ __launch_bounds__(256) void k1_fwd_kernel(
    const float* __restrict__ x1, const float* __restrict__ x2,
    const float* __restrict__ W1, const float* __restrict__ b1,
    const float* __restrict__ W2, const float* __restrict__ b2,
    const float* __restrict__ W3,
    float* __restrict__ h1o, float* __restrict__ S1o, float* __restrict__ h2o,
    float* __restrict__ G2L, float* __restrict__ dots)
{
    int t = threadIdx.x;
    if (blockIdx.x < 16) {
        int s0 = blockIdx.x * 8;
        const float* xrow[8];
        #pragma unroll
        for (int r = 0; r < 8; ++r) {
            int s = s0 + r;
            xrow[r] = (s < NS) ? (x1 + s * D) : (x2 + (s - NS) * D);
        }
        // ---- layer 1: acc[r] = x[r] . W1[:,t] ----
        float acc[8];
        float bv = b1[t];
        #pragma unroll
        for (int r = 0; r < 8; ++r) acc[r] = bv;
        #pragma unroll 4
        for (int k = 0; k < D; ++k) {
            float w = W1[k * D + t];
            #pragma unroll
            for (int r = 0; r < 8; ++r) acc[r] = fmaf(xrow[r][k], w, acc[r]);
        }
        #pragma unroll
        for (int r = 0; r < 8; ++r) {
            float h = tanhf(acc[r]);
            int s = s0 + r;
            h1o[s * D + t] = h;
            S1o[s * D + t] = 1.0f - h * h;
        }
        __syncthreads();   // h1o rows for this block fully written (drains vmem)
        // ---- layer 2: acc[r] = h1[r] . W2[:,t] ----
        bv = b2[t];
        #pragma unroll
        for (int r = 0; r < 8; ++r) acc[r] = bv;
        #pragma unroll 4
        for (int k = 0; k < D; ++k) {
            float w = W2[k * D + t];
            #pragma unroll
            for (int r = 0; r < 8; ++r) acc[r] = fmaf(h1o[(s0 + r) * D + k], w, acc[r]);
        }
        float w3[O];
        #pragma unroll
        for (int a = 0; a < O; ++a) w3[a] = W3[t * O + a];
        #pragma unroll
        for (int r = 0; r < 8; ++r) {
            float h = tanhf(acc[r]);
            int s = s0 + r;
            h2o[s * D + t] = h;
            float s2 = 1.0f - h * h;
            #pragma unroll
            for (int a = 0; a < O; ++a)
                G2L[(s * O + a) * D + t] = s2 * w3[a];   // [(s,a)][i] layout
        }
    } else {
        // x-dots: dots[0][n][m] = x1[n].x2[m]; 4 n per block
        int n0 = (blockIdx.x - 16) * 4;
        __shared__ float as[D];
        int wave = t >> 6, lane = t & 63;
        for (int nn = 0; nn < 4; ++nn) {
            int n = n0 + nn;
            __syncthreads();
            as[t] = x1[n * D + t];
            __syncthreads();
            for (int m = wave; m < NS; m += 4) {
                const float* Bv = x2 + m * D;
                float v = as[lane] * Bv[lane]
                        + as[64 + lane] * Bv[64 + lane]
                        + as[128 + lane] * Bv[128 + lane]
                        + as[192 + lane] * Bv[192 + lane];
                #pragma unroll
                for (int off = 32; off > 0; off >>= 1) v += __shfl_xor(v, off);
                if (lane == 0) dots[0 * NS * NS + n * NS + m] = v;
            }
        }
    }
}

// ============ K2: backward as one 1280x256x256 NT GEMM + h-dots ===========
// M1[(s,a),i] = S1[s,i] * sum_j M2[(s,a),j] * W2[i,j]  (W2 rows K-contiguous)
// Blocks 0..79: 64x64 tiles (20 row-tiles x 4 col-tiles).
// Blocks 80..111: h1-dots / h2-dots, 4 n per block.
__global__ __launch_bounds__(256) void k2_bwd_kernel(
    const float* __restrict__ G2L, const float* __restrict__ W2,
    const float* __restrict__ S1, float* __restrict__ G1L,
    const float* __restrict__ h1o, const float* __restrict__ h2o,
    float* __restrict__ dots)
{
    int t = threadIdx.x;
    if (blockIdx.x < 80) {
        int by = blockIdx.x >> 2, bx = blockIdx.x & 3;
        __shared__ float As[64 * LSTR], Bs[64 * LSTR];   // 18 KB
        int tx = t & 15, ty = t >> 4;
        float acc[4][4];
        #pragma unroll
        for (int i = 0; i < 4; ++i)
            #pragma unroll
            for (int j = 0; j < 4; ++j) acc[i][j] = 0.0f;

        const float* arow = G2L + (by * 64) * D;
        const float* brow = W2 + (bx * 64) * D;
        for (int kc = 0; kc < D; kc += TK) {
            __syncthreads();
            #pragma unroll
            for (int u = 0; u < 2; ++u) {
                int idx = t + u * 256;
                int r = idx >> 3, c4 = idx & 7;
                int goff = r * D + kc + c4 * 4;
                int loff = r * LSTR + c4 * 4;
                *(float4*)&As[loff] = *(const float4*)&arow[goff];
                *(float4*)&Bs[loff] = *(const float4*)&brow[goff];
            }
            __syncthreads();
            #pragma unroll
            for (int kk = 0; kk < TK; kk += 4) {
                float4 a[4], b[4];
                #pragma unroll
                for (int i = 0; i < 4; ++i)
                    a[i] = *(const float4*)&As[(4 * ty + i) * LSTR + kk];
                #pragma unroll
                for (int j = 0; j < 4; ++j)
                    b[j] = *(const float4*)&Bs[(tx + 16 * j) * LSTR + kk];
                #pragma unroll
                for (int i = 0; i < 4; ++i)
                    #pragma unroll
                    for (int j = 0; j < 4; ++j) {
                        acc[i][j] = fmaf(a[i].x, b[j].x, acc[i][j]);
                        acc[i][j] = fmaf(a[i].y, b[j].y, acc[i][j]);
                        acc[i][j] = fmaf(a[i].z, b[j].z, acc[i][j]);
                        acc[i][j] = fmaf(a[i].w, b[j].w, acc[i][j]);
                    }
            }
        }
        #pragma unroll
        for (int i = 0; i < 4; ++i) {
            int R = by * 64 + 4 * ty + i;
            int s = R / O;
            #pragma unroll
            for (int j = 0; j < 4; ++j) {
                int col = bx * 64 + tx + 16 * j;
                G1L[R * D + col] = acc[i][j] * S1[s * D + col];
            }
        }
    } else {
        int idx = blockIdx.x - 80;             // 0..31
        int which = 1 + (idx >> 4);            // 1: h1, 2: h2
        int n0 = (idx & 15) * 4;
        const float* Ab = (which == 1) ? h1o : h2o;
        const float* B = Ab + NS * D;
        __shared__ float as[D];
        int wave = t >> 6, lane = t & 63;
        for (int nn = 0; nn < 4; ++nn) {
            int n = n0 + nn;
            __syncthreads();
            as[t] = Ab[n * D + t];
            __syncthreads();
            for (int m = wave; m < NS; m += 4) {
                const float* Bv = B + m * D;
                float v = as[lane] * Bv[lane]
                        + as[64 + lane] * Bv[64 + lane]
                        + as[128 + lane] * Bv[128 + lane]
                        + as[192 + lane] * Bv[192 + lane];
                #pragma unroll
                for (int off = 32; off > 0; off >>= 1) v += __shfl_xor(v, off);
                if (lane == 0) dots[(which * NS + n) * NS + m] = v;
            }
        }
    }
}

// ============ K3: dual 640x640x256 GEMM + NTK epilogue (32x64 tiles) ======
__global__ __launch_bounds__(256) void k3_gemm_kernel(
    const float* __restrict__ G1L, const float* __restrict__ G2L,
    const float* __restrict__ dots, float* __restrict__ out)
{
    int by = blockIdx.x / 10, bx = blockIdx.x % 10;     // 20 x 10 = 200 blocks
    __shared__ float A1[32 * LSTR], B1[64 * LSTR], A2[32 * LSTR], B2[64 * LSTR];
    int t = threadIdx.x;
    int tx = t & 15, ty = t >> 4;                        // 2 rows x 4 cols / thread

    float acc1[2][4], acc2[2][4];
    #pragma unroll
    for (int i = 0; i < 2; ++i)
        #pragma unroll
        for (int j = 0; j < 4; ++j) { acc1[i][j] = 0.0f; acc2[i][j] = 0.0f; }

    const float* arow1 = G1L + (by * 32) * D;
    const float* brow1 = G1L + (640 + bx * 64) * D;
    const float* arow2 = G2L + (by * 32) * D;
    const float* brow2 = G2L + (640 + bx * 64) * D;

    for (int kc = 0; kc < D; kc += TK) {
        __syncthreads();
        {   // A tiles: 32x32 = 256 float4 -> 1/thread
            int r = t >> 3, c4 = t & 7;
            int goff = r * D + kc + c4 * 4;
            int loff = r * LSTR + c4 * 4;
            *(float4*)&A1[loff] = *(const float4*)&arow1[goff];
            *(float4*)&A2[loff] = *(const float4*)&arow2[goff];
        }
        #pragma unroll
        for (int u = 0; u < 2; ++u) {   // B tiles: 64x32 = 512 float4 -> 2/thread
            int idx = t + u * 256;
            int r = idx >> 3, c4 = idx & 7;
            int goff = r * D + kc + c4 * 4;
            int loff = r * LSTR + c4 * 4;
            *(float4*)&B1[loff] = *(const float4*)&brow1[goff];
            *(float4*)&B2[loff] = *(const float4*)&brow2[goff];
        }
        __syncthreads();
        #pragma unroll
        for (int kk = 0; kk < TK; kk += 4) {
            float4 a1[2], a2[2], b1v[4], b2v[4];
            #pragma unroll
            for (int i = 0; i < 2; ++i) {
                a1[i] = *(const float4*)&A1[(2 * ty + i) * LSTR + kk];
                a2[i] = *(const float4*)&A2[(2 * ty + i) * LSTR + kk];
            }
            #pragma unroll
            for (int j = 0; j < 4; ++j) {
                b1v[j] = *(const float4*)&B1[(tx + 16 * j) * LSTR + kk];
                b2v[j] = *(const float4*)&B2[(tx + 16 * j) * LSTR + kk];
            }
            #pragma unroll
            for (int i = 0; i < 2; ++i)
                #pragma unroll
                for (int j = 0; j < 4; ++j) {
                    acc1[i][j] = fmaf(a1[i].x, b1v[j].x, acc1[i][j]);
                    acc1[i][j] = fmaf(a1[i].y, b1v[j].y, acc1[i][j]);
                    acc1[i][j] = fmaf(a1[i].z, b1v[j].z, acc1[i][j]);
                    acc1[i][j] = fmaf(a1[i].w, b1v[j].w, acc1[i][j]);
                    acc2[i][j] = fmaf(a2[i].x, b2v[j].x, acc2[i][j]);
                    acc2[i][j] = fmaf(a2[i].y, b2v[j].y, acc2[i][j]);
                    acc2[i][j] = fmaf(a2[i].z, b2v[j].z, acc2[i][j]);
                    acc2[i][j] = fmaf(a2[i].w, b2v[j].w, acc2[i][j]);
                }
        }
    }

    #pragma unroll
    for (int i = 0; i < 2; ++i) {
        int R = by * 32 + 2 * ty + i;
        int n = R / O, a = R - n * O;
        #pragma unroll
        for (int j = 0; j < 4; ++j) {
            int C = bx * 64 + tx + 16 * j;
            int m = C / O, b = C - m * O;
            float cx  = 1.0f + dots[0 * NS * NS + n * NS + m];
            float ch1 = 1.0f + dots[1 * NS * NS + n * NS + m];
            float val = cx * acc1[i][j] + ch1 * acc2[i][j];
            if (a == b) val += 1.0f + dots[2 * NS * NS + n * NS + m];
            out[(n * NS + m) * (O * O) + a * O + b] = val;
        }
    }
}

extern "C" void kernel_launch(void* const* d_in, const int* in_sizes, int n_in,
                              void* d_out, int out_size, void* d_ws, size_t ws_size,
                              hipStream_t stream) {
    const float* x1 = (const float*)d_in[0];
    const float* x2 = (const float*)d_in[1];
    const float* W1 = (const float*)d_in[2];
    const float* b1 = (const float*)d_in[3];
    const float* W2 = (const float*)d_in[4];
    const float* b2 = (const float*)d_in[5];
    const float* W3 = (const float*)d_in[6];
    // b3 (d_in[7]) does not enter the Jacobian.

    float* ws   = (float*)d_ws;
    float* h1   = ws;                     // 128*256
    float* S1   = h1 + 128 * D;           // 128*256
    float* h2   = S1 + 128 * D;           // 128*256
    float* G2L  = h2 + 128 * D;           // 1280*256  ([s*O+a][i])
    float* G1L  = G2L + 1280 * D;         // 1280*256
    float* dots = G1L + 1280 * D;         // 3*64*64
    float* out  = (float*)d_out;

    hipLaunchKernelGGL(k1_fwd_kernel, dim3(32), dim3(256), 0, stream,
                       x1, x2, W1, b1, W2, b2, W3, h1, S1, h2, G2L, dots);
    hipLaunchKernelGGL(k2_bwd_kernel, dim3(112), dim3(256), 0, stream,
                       G2L, W2, S1, G1L, h1, h2, dots);
    hipLaunchKernelGGL(k3_gemm_kernel, dim3(200), dim3(256), 0, stream,
                       G1L, G2L, dots, out);
}